// Round 1
// baseline (557.014 us; speedup 1.0000x reference)
//
#include <hip/hip_runtime.h>
#include <hip/hip_bf16.h>

typedef unsigned short u16;
typedef __attribute__((ext_vector_type(8))) __bf16 bf16x8;
typedef __attribute__((ext_vector_type(4))) float f32x4;

#define DEV __device__ __forceinline__

DEV u16 f2bf(float f) {
  union { float f; unsigned int u; } v; v.f = f;
  unsigned int x = v.u;
  return (u16)((x + 0x7fffu + ((x >> 16) & 1u)) >> 16);  // RNE
}

DEV void gload_lds16(const u16* g, u16* l) {
  __builtin_amdgcn_global_load_lds(
      (__attribute__((address_space(1))) void*)(g),
      (__attribute__((address_space(3))) void*)(l), 16, 0, 0);
}

// ---------------- LayerNorm + cast to bf16 ----------------
// one block per row; C = NV*1024 floats per row
template <int NV>
__global__ __launch_bounds__(256) void ln_cast(const float* __restrict__ x,
                                               const float* __restrict__ g,
                                               const float* __restrict__ b,
                                               u16* __restrict__ out, int C) {
  int row = blockIdx.x;
  int tid = threadIdx.x;
  const float4* xr = (const float4*)(x + (size_t)row * C);
  float4 v[NV];
  float s = 0.f, ss = 0.f;
#pragma unroll
  for (int i = 0; i < NV; i++) {
    v[i] = xr[tid + i * 256];
    s += v[i].x + v[i].y + v[i].z + v[i].w;
    ss += v[i].x * v[i].x + v[i].y * v[i].y + v[i].z * v[i].z + v[i].w * v[i].w;
  }
#pragma unroll
  for (int off = 32; off > 0; off >>= 1) {
    s += __shfl_down(s, off);
    ss += __shfl_down(ss, off);
  }
  __shared__ float red[8];
  int wv = tid >> 6;
  if ((tid & 63) == 0) { red[wv] = s; red[4 + wv] = ss; }
  __syncthreads();
  float S = red[0] + red[1] + red[2] + red[3];
  float SS = red[4] + red[5] + red[6] + red[7];
  float mu = S / C;
  float rstd = rsqrtf(SS / C - mu * mu + 1e-5f);
  const float4* gr = (const float4*)g;
  const float4* br = (const float4*)b;
  ushort4* orow = (ushort4*)(out + (size_t)row * C);
#pragma unroll
  for (int i = 0; i < NV; i++) {
    int gi = tid + i * 256;
    float4 gv = gr[gi], bv = br[gi];
    ushort4 o;
    o.x = f2bf((v[i].x - mu) * rstd * gv.x + bv.x);
    o.y = f2bf((v[i].y - mu) * rstd * gv.y + bv.y);
    o.z = f2bf((v[i].z - mu) * rstd * gv.z + bv.z);
    o.w = f2bf((v[i].w - mu) * rstd * gv.w + bv.w);
    orow[gi] = o;
  }
}

// ---------------- transpose + cast f32 -> bf16 ----------------
// in [K][N] f32 row-major -> out [N][K] bf16 row-major. grid (N/32, K/32)
__global__ __launch_bounds__(256) void transpose_cast(const float* __restrict__ in,
                                                      u16* __restrict__ out,
                                                      int K, int N) {
  __shared__ float t[32][33];
  int tx = threadIdx.x & 31, ty = threadIdx.x >> 5;  // ty 0..7
  int n0 = blockIdx.x * 32, k0 = blockIdx.y * 32;
#pragma unroll
  for (int i = 0; i < 32; i += 8)
    t[ty + i][tx] = in[(size_t)(k0 + ty + i) * N + n0 + tx];
  __syncthreads();
#pragma unroll
  for (int i = 0; i < 32; i += 8)
    out[(size_t)(n0 + ty + i) * K + k0 + tx] = f2bf(t[tx][ty + i]);
}

// ---------------- build VT[bh][128][1024] from KV ----------------
// V lives at KV[(b*1024+s)*4096 + 2048 + h*128 + d]. grid (4, 32, 32)
__global__ __launch_bounds__(256) void build_vt(const u16* __restrict__ KV,
                                                u16* __restrict__ VT) {
  __shared__ u16 t[32][33];
  int bh = blockIdx.z, b = bh >> 4, h = bh & 15;
  int d0 = blockIdx.x * 32, s0 = blockIdx.y * 32;
  int tx = threadIdx.x & 31, ty = threadIdx.x >> 5;
  const u16* src = KV + (size_t)(b * 1024) * 4096 + 2048 + h * 128;
#pragma unroll
  for (int i = 0; i < 32; i += 8)
    t[ty + i][tx] = src[(size_t)(s0 + ty + i) * 4096 + d0 + tx];
  __syncthreads();
  u16* dst = VT + (size_t)bh * (128 * 1024);
#pragma unroll
  for (int i = 0; i < 32; i += 8)
    dst[(size_t)(d0 + ty + i) * 1024 + s0 + tx] = t[tx][ty + i];
}

// ---------------- GEMM: C[M,N] = A[M,K] * BT[N,K]^T  (bf16 in, fp32 acc) ----------------
DEV void storeC(u16* C, size_t idx, float v) { C[idx] = f2bf(v); }
DEV void storeC(float* C, size_t idx, float v) { C[idx] = v; }

template <typename OutT>
__global__ __launch_bounds__(256) void gemm_bt(const u16* __restrict__ A,
                                               const u16* __restrict__ BT,
                                               OutT* __restrict__ C,
                                               int M, int N, int K) {
  constexpr int BK = 32;
  __shared__ __attribute__((aligned(16))) u16 As[128 * BK];
  __shared__ __attribute__((aligned(16))) u16 Bs[128 * BK];
  int tilesN = N >> 7;
  int bm = (blockIdx.x / tilesN) << 7;
  int bn = (blockIdx.x % tilesN) << 7;
  int tid = threadIdx.x;
  int lane = tid & 63, wave = tid >> 6;
  int wm = (wave >> 1) << 6, wn = (wave & 1) << 6;
  int srow = wave * 16 + (lane >> 2);
  int scol = (lane & 3) * 8;
  int fr = lane & 15, fk = (lane >> 4) * 8;
  const u16* Ab = A + (size_t)bm * K;
  const u16* Bb = BT + (size_t)bn * K;
  f32x4 acc[4][4] = {};

  for (int kt = 0; kt < K; kt += BK) {
#pragma unroll
    for (int j = 0; j < 2; j++) {
      gload_lds16(Ab + (size_t)(j * 64 + srow) * K + kt + scol,
                  &As[(j * 64 + wave * 16) * BK]);
      gload_lds16(Bb + (size_t)(j * 64 + srow) * K + kt + scol,
                  &Bs[(j * 64 + wave * 16) * BK]);
    }
    __syncthreads();
    bf16x8 af[4], bfr[4];
#pragma unroll
    for (int m = 0; m < 4; m++)
      af[m] = *(const bf16x8*)&As[(wm + m * 16 + fr) * BK + fk];
#pragma unroll
    for (int n = 0; n < 4; n++)
      bfr[n] = *(const bf16x8*)&Bs[(wn + n * 16 + fr) * BK + fk];
#pragma unroll
    for (int m = 0; m < 4; m++)
#pragma unroll
      for (int n = 0; n < 4; n++)
        acc[m][n] = __builtin_amdgcn_mfma_f32_16x16x32_bf16(af[m], bfr[n], acc[m][n], 0, 0, 0);
    __syncthreads();
  }

#pragma unroll
  for (int m = 0; m < 4; m++) {
    int rbase = bm + wm + m * 16 + ((lane >> 4) << 2);
#pragma unroll
    for (int n = 0; n < 4; n++) {
      int col = bn + wn + n * 16 + fr;
#pragma unroll
      for (int r = 0; r < 4; r++)
        storeC(C, (size_t)(rbase + r) * N + col, acc[m][n][r]);
    }
  }
}

// ---------------- fused flash attention ----------------
// Q [B*SQ][2048] (head h at col h*128), KV [B*SKV][4096] (K at h*128),
// VT [bh][128][1024], O [B*SQ][2048]. grid = B*H*(SQ/64), block 256 (4 waves x 16 q-rows)
__global__ __launch_bounds__(256) void attn_kernel(const u16* __restrict__ Q,
                                                   const u16* __restrict__ KV,
                                                   const u16* __restrict__ VT,
                                                   u16* __restrict__ O) {
  const int SQ = 2048, SKV = 1024;
  int qt = blockIdx.x & 31, bh = blockIdx.x >> 5;
  int b = bh >> 4, h = bh & 15;
  int wave = threadIdx.x >> 6, lane = threadIdx.x & 63;
  int q0 = qt * 64 + wave * 16;
  int fr = lane & 15, fkb = (lane >> 4) * 8;
  const float sc = 0.08838834764831845f;  // 1/sqrt(128)

  const u16* Qbase = Q + (size_t)(b * SQ + q0 + fr) * 2048 + h * 128;
  bf16x8 qf[4];
#pragma unroll
  for (int kd = 0; kd < 4; kd++)
    qf[kd] = *(const bf16x8*)(Qbase + kd * 32 + fkb);

  const u16* Kb = KV + (size_t)(b * SKV) * 4096 + h * 128;
  const u16* Vt = VT + (size_t)bh * (128 * 1024);

  __shared__ __attribute__((aligned(16))) u16 Pb[4][16 * 32];
  u16* P = &Pb[wave][0];

  f32x4 o[8] = {};
  float mrun[4] = {-1e30f, -1e30f, -1e30f, -1e30f};
  float lrun[4] = {0.f, 0.f, 0.f, 0.f};

  for (int kv0 = 0; kv0 < SKV; kv0 += 32) {
    f32x4 s[2];
#pragma unroll
    for (int sub = 0; sub < 2; sub++) {
      f32x4 a = {};
      const u16* Kr = Kb + (size_t)(kv0 + sub * 16 + fr) * 4096;
#pragma unroll
      for (int kd = 0; kd < 4; kd++) {
        bf16x8 kf = *(const bf16x8*)(Kr + kd * 32 + fkb);
        a = __builtin_amdgcn_mfma_f32_16x16x32_bf16(qf[kd], kf, a, 0, 0, 0);
      }
      s[sub] = a * sc;
    }
    float corr[4];
#pragma unroll
    for (int r = 0; r < 4; r++) {
      float pm = fmaxf(s[0][r], s[1][r]);
#pragma unroll
      for (int off = 1; off < 16; off <<= 1) pm = fmaxf(pm, __shfl_xor(pm, off));
      float mn = fmaxf(mrun[r], pm);
      corr[r] = __expf(mrun[r] - mn);
      mrun[r] = mn;
      float p0 = __expf(s[0][r] - mn);
      float p1 = __expf(s[1][r] - mn);
      lrun[r] = lrun[r] * corr[r] + p0 + p1;
      int qrow = ((lane >> 4) << 2) + r;
      P[qrow * 32 + fr] = f2bf(p0);
      P[qrow * 32 + 16 + fr] = f2bf(p1);
    }
#pragma unroll
    for (int n = 0; n < 8; n++) {
      o[n][0] *= corr[0]; o[n][1] *= corr[1];
      o[n][2] *= corr[2]; o[n][3] *= corr[3];
    }
    asm volatile("s_waitcnt lgkmcnt(0)" ::: "memory");
    bf16x8 pa = *(const bf16x8*)&P[fr * 32 + fkb];
#pragma unroll
    for (int n = 0; n < 8; n++) {
      bf16x8 vf = *(const bf16x8*)(Vt + (size_t)(n * 16 + fr) * 1024 + kv0 + fkb);
      o[n] = __builtin_amdgcn_mfma_f32_16x16x32_bf16(pa, vf, o[n], 0, 0, 0);
    }
  }

#pragma unroll
  for (int r = 0; r < 4; r++) {
    float lt = lrun[r];
#pragma unroll
    for (int off = 1; off < 16; off <<= 1) lt += __shfl_xor(lt, off);
    float inv = 1.0f / lt;
    int row = b * SQ + q0 + ((lane >> 4) << 2) + r;
    u16* Or = O + (size_t)row * 2048 + h * 128;
#pragma unroll
    for (int n = 0; n < 8; n++) Or[n * 16 + fr] = f2bf(o[n][r] * inv);
  }
}

// ---------------- launch ----------------
extern "C" void kernel_launch(void* const* d_in, const int* in_sizes, int n_in,
                              void* d_out, int out_size, void* d_ws, size_t ws_size,
                              hipStream_t stream) {
  const float* image_embeds  = (const float*)d_in[0];  // [2,1024,2048]
  const float* hidden_states = (const float*)d_in[1];  // [2,2048,3072]
  const float* Wq   = (const float*)d_in[2];           // [3072,2048]
  const float* Wkv  = (const float*)d_in[3];           // [2048,4096]
  const float* Wout = (const float*)d_in[4];           // [2048,3072]
  const float* ln1_g = (const float*)d_in[5];
  const float* ln1_b = (const float*)d_in[6];
  const float* ln2_g = (const float*)d_in[7];
  const float* ln2_b = (const float*)d_in[8];
  float* out = (float*)d_out;

  char* ws = (char*)d_ws;
  size_t off = 0;
  auto alloc = [&](size_t bytes) {
    void* p = ws + off;
    off += (bytes + 255) & ~(size_t)255;
    return p;
  };
  u16* Xq   = (u16*)alloc((size_t)4096 * 3072 * 2);  // LN(hidden) bf16; reused as AO
  u16* Xkv  = (u16*)alloc((size_t)2048 * 2048 * 2);  // LN(image) bf16
  u16* WqT  = (u16*)alloc((size_t)2048 * 3072 * 2);  // Wq^T bf16; reused as VT
  u16* WkvT = (u16*)alloc((size_t)4096 * 2048 * 2);  // Wkv^T bf16
  u16* WoT  = (u16*)alloc((size_t)3072 * 2048 * 2);  // Wout^T bf16
  u16* Qb   = (u16*)alloc((size_t)4096 * 2048 * 2);  // q bf16
  u16* KVb  = (u16*)alloc((size_t)2048 * 4096 * 2);  // kv bf16
  u16* VTb  = WqT;   // alias: WqT dead after q-gemm
  u16* AO   = Xq;    // alias: Xq dead after q-gemm; AO <= Xq size

  ln_cast<3><<<4096, 256, 0, stream>>>(hidden_states, ln2_g, ln2_b, Xq, 3072);
  ln_cast<2><<<2048, 256, 0, stream>>>(image_embeds, ln1_g, ln1_b, Xkv, 2048);
  transpose_cast<<<dim3(2048 / 32, 3072 / 32), 256, 0, stream>>>(Wq, WqT, 3072, 2048);
  transpose_cast<<<dim3(4096 / 32, 2048 / 32), 256, 0, stream>>>(Wkv, WkvT, 2048, 4096);
  transpose_cast<<<dim3(3072 / 32, 2048 / 32), 256, 0, stream>>>(Wout, WoT, 2048, 3072);

  gemm_bt<u16><<<(4096 / 128) * (2048 / 128), 256, 0, stream>>>(Xq, WqT, Qb, 4096, 2048, 3072);
  gemm_bt<u16><<<(2048 / 128) * (4096 / 128), 256, 0, stream>>>(Xkv, WkvT, KVb, 2048, 4096, 2048);

  build_vt<<<dim3(4, 32, 32), 256, 0, stream>>>(KVb, VTb);
  attn_kernel<<<32 * 32, 256, 0, stream>>>(Qb, KVb, VTb, AO);

  gemm_bt<float><<<(4096 / 128) * (3072 / 128), 256, 0, stream>>>(AO, WoT, out, 4096, 3072, 2048);
}

// Round 2
// 451.397 us; speedup vs baseline: 1.2340x; 1.2340x over previous
//
#include <hip/hip_runtime.h>
#include <hip/hip_bf16.h>

typedef unsigned short u16;
typedef __attribute__((ext_vector_type(8))) __bf16 bf16x8;
typedef __attribute__((ext_vector_type(4))) float f32x4;

#define DEV __device__ __forceinline__

DEV u16 f2bf(float f) {
  union { float f; unsigned int u; } v; v.f = f;
  unsigned int x = v.u;
  return (u16)((x + 0x7fffu + ((x >> 16) & 1u)) >> 16);  // RNE
}

DEV void gload_lds16(const u16* g, u16* l) {
  __builtin_amdgcn_global_load_lds(
      (__attribute__((address_space(1))) void*)(g),
      (__attribute__((address_space(3))) void*)(l), 16, 0, 0);
}

// ---------------- LayerNorm + cast to bf16 ----------------
template <int NV>
__global__ __launch_bounds__(256) void ln_cast(const float* __restrict__ x,
                                               const float* __restrict__ g,
                                               const float* __restrict__ b,
                                               u16* __restrict__ out, int C) {
  int row = blockIdx.x;
  int tid = threadIdx.x;
  const float4* xr = (const float4*)(x + (size_t)row * C);
  float4 v[NV];
  float s = 0.f, ss = 0.f;
#pragma unroll
  for (int i = 0; i < NV; i++) {
    v[i] = xr[tid + i * 256];
    s += v[i].x + v[i].y + v[i].z + v[i].w;
    ss += v[i].x * v[i].x + v[i].y * v[i].y + v[i].z * v[i].z + v[i].w * v[i].w;
  }
#pragma unroll
  for (int off = 32; off > 0; off >>= 1) {
    s += __shfl_down(s, off);
    ss += __shfl_down(ss, off);
  }
  __shared__ float red[8];
  int wv = tid >> 6;
  if ((tid & 63) == 0) { red[wv] = s; red[4 + wv] = ss; }
  __syncthreads();
  float S = red[0] + red[1] + red[2] + red[3];
  float SS = red[4] + red[5] + red[6] + red[7];
  float mu = S / C;
  float rstd = rsqrtf(SS / C - mu * mu + 1e-5f);
  const float4* gr = (const float4*)g;
  const float4* br = (const float4*)b;
  ushort4* orow = (ushort4*)(out + (size_t)row * C);
#pragma unroll
  for (int i = 0; i < NV; i++) {
    int gi = tid + i * 256;
    float4 gv = gr[gi], bv = br[gi];
    ushort4 o;
    o.x = f2bf((v[i].x - mu) * rstd * gv.x + bv.x);
    o.y = f2bf((v[i].y - mu) * rstd * gv.y + bv.y);
    o.z = f2bf((v[i].z - mu) * rstd * gv.z + bv.z);
    o.w = f2bf((v[i].w - mu) * rstd * gv.w + bv.w);
    orow[gi] = o;
  }
}

// ---------------- transpose + cast f32 -> bf16 ----------------
__global__ __launch_bounds__(256) void transpose_cast(const float* __restrict__ in,
                                                      u16* __restrict__ out,
                                                      int K, int N) {
  __shared__ float t[32][33];
  int tx = threadIdx.x & 31, ty = threadIdx.x >> 5;
  int n0 = blockIdx.x * 32, k0 = blockIdx.y * 32;
#pragma unroll
  for (int i = 0; i < 32; i += 8)
    t[ty + i][tx] = in[(size_t)(k0 + ty + i) * N + n0 + tx];
  __syncthreads();
#pragma unroll
  for (int i = 0; i < 32; i += 8)
    out[(size_t)(n0 + ty + i) * K + k0 + tx] = f2bf(t[tx][ty + i]);
}

// ---------------- build VT[bh][128][1024] from KV ----------------
__global__ __launch_bounds__(256) void build_vt(const u16* __restrict__ KV,
                                                u16* __restrict__ VT) {
  __shared__ u16 t[32][33];
  int bh = blockIdx.z, b = bh >> 4, h = bh & 15;
  int d0 = blockIdx.x * 32, s0 = blockIdx.y * 32;
  int tx = threadIdx.x & 31, ty = threadIdx.x >> 5;
  const u16* src = KV + (size_t)(b * 1024) * 4096 + 2048 + h * 128;
#pragma unroll
  for (int i = 0; i < 32; i += 8)
    t[ty + i][tx] = src[(size_t)(s0 + ty + i) * 4096 + d0 + tx];
  __syncthreads();
  u16* dst = VT + (size_t)bh * (128 * 1024);
#pragma unroll
  for (int i = 0; i < 32; i += 8)
    dst[(size_t)(d0 + ty + i) * 1024 + s0 + tx] = t[tx][ty + i];
}

// ---------------- GEMM: C[M,N] = A[M,K] * BT[N,K]^T ----------------
DEV void storeC(u16* C, size_t idx, float v) { C[idx] = f2bf(v); }
DEV void storeC(float* C, size_t idx, float v) { C[idx] = v; }

template <typename OutT>
__global__ __launch_bounds__(256) void gemm_bt(const u16* __restrict__ A,
                                               const u16* __restrict__ BT,
                                               OutT* __restrict__ C,
                                               int M, int N, int K) {
  constexpr int BK = 32;
  __shared__ __attribute__((aligned(16))) u16 As[128 * BK];
  __shared__ __attribute__((aligned(16))) u16 Bs[128 * BK];
  int tilesN = N >> 7;
  int bm = (blockIdx.x / tilesN) << 7;
  int bn = (blockIdx.x % tilesN) << 7;
  int tid = threadIdx.x;
  int lane = tid & 63, wave = tid >> 6;
  int wm = (wave >> 1) << 6, wn = (wave & 1) << 6;
  int srow = wave * 16 + (lane >> 2);
  int scol = (lane & 3) * 8;
  int fr = lane & 15, fk = (lane >> 4) * 8;
  const u16* Ab = A + (size_t)bm * K;
  const u16* Bb = BT + (size_t)bn * K;
  f32x4 acc[4][4] = {};

  for (int kt = 0; kt < K; kt += BK) {
#pragma unroll
    for (int j = 0; j < 2; j++) {
      gload_lds16(Ab + (size_t)(j * 64 + srow) * K + kt + scol,
                  &As[(j * 64 + wave * 16) * BK]);
      gload_lds16(Bb + (size_t)(j * 64 + srow) * K + kt + scol,
                  &Bs[(j * 64 + wave * 16) * BK]);
    }
    __syncthreads();
    bf16x8 af[4], bfr[4];
#pragma unroll
    for (int m = 0; m < 4; m++)
      af[m] = *(const bf16x8*)&As[(wm + m * 16 + fr) * BK + fk];
#pragma unroll
    for (int n = 0; n < 4; n++)
      bfr[n] = *(const bf16x8*)&Bs[(wn + n * 16 + fr) * BK + fk];
#pragma unroll
    for (int m = 0; m < 4; m++)
#pragma unroll
      for (int n = 0; n < 4; n++)
        acc[m][n] = __builtin_amdgcn_mfma_f32_16x16x32_bf16(af[m], bfr[n], acc[m][n], 0, 0, 0);
    __syncthreads();
  }

#pragma unroll
  for (int m = 0; m < 4; m++) {
    int rbase = bm + wm + m * 16 + ((lane >> 4) << 2);
#pragma unroll
    for (int n = 0; n < 4; n++) {
      int col = bn + wn + n * 16 + fr;
#pragma unroll
      for (int r = 0; r < 4; r++)
        storeC(C, (size_t)(rbase + r) * N + col, acc[m][n][r]);
    }
  }
}

// ---------------- fused flash attention (v2) ----------------
// Q [B*SQ][2048], KV [B*SKV][4096] (K at col h*128), VT [bh][128][1024],
// O [B*SQ][2048]. grid = B*H*(SQ/64), block 256 (4 waves x 16 q-rows each).
// K staged in LDS (double-buffered, KVBLK=64) via global_load_lds with
// pre-swizzled source (block ^= row&7) so ds_read_b128 is conflict-floor.
__global__ __launch_bounds__(256) void attn_kernel(const u16* __restrict__ Q,
                                                   const u16* __restrict__ KV,
                                                   const u16* __restrict__ VT,
                                                   u16* __restrict__ O) {
  const int SQ = 2048, SKV = 1024;
  const int NCHUNK = SKV / 64;
  int qt = blockIdx.x & 31, bh = blockIdx.x >> 5;
  int b = bh >> 4, h = bh & 15;
  int wave = threadIdx.x >> 6, lane = threadIdx.x & 63;
  int q0 = qt * 64 + wave * 16;
  int fr = lane & 15, g = lane >> 4, fkb = g * 8;
  const float sc = 0.08838834764831845f;  // 1/sqrt(128)

  __shared__ __attribute__((aligned(16))) u16 Ks[2][64 * 128];
  __shared__ __attribute__((aligned(16))) u16 Pb[4][16 * 72];  // 72 = 64 + 8 pad (keeps 16B align)
  u16* P = &Pb[wave][0];

  // Q fragments (held for whole kernel)
  const u16* Qbase = Q + (size_t)(b * SQ + q0 + fr) * 2048 + h * 128;
  bf16x8 qf[4];
#pragma unroll
  for (int kd = 0; kd < 4; kd++)
    qf[kd] = *(const bf16x8*)(Qbase + kd * 32 + fkb);

  const u16* Kb = KV + (size_t)(b * SKV) * 4096 + h * 128;
  const u16* Vt = VT + (size_t)bh * (128 * 1024);

  // stage chunk c into Ks[buf]: wave stages rows wave*16..wave*16+15 (4 instrs)
  // lane i writes physical 16B-block (i&15) of row r; source block = (i&15)^(r&7)
  auto stage = [&](int c, int buf) {
#pragma unroll
    for (int j = 0; j < 4; j++) {
      int r = wave * 16 + j * 4 + g;
      int gb = (lane & 15) ^ (r & 7);
      gload_lds16(Kb + (size_t)(c * 64 + r) * 4096 + gb * 8,
                  &Ks[buf][(wave * 16 + j * 4) * 128]);
    }
  };

  f32x4 o[8] = {};
  float mrun[4] = {-1e30f, -1e30f, -1e30f, -1e30f};
  float lrun[4] = {0.f, 0.f, 0.f, 0.f};

  stage(0, 0);
  __syncthreads();
  int buf = 0;

  for (int c = 0; c < NCHUNK; c++) {
    if (c + 1 < NCHUNK) stage(c + 1, buf ^ 1);

    // QK^T: acc[n][r] = S[q=g*4+r][kv=n*16+fr] (pre-scale)
    f32x4 acc[4] = {};
#pragma unroll
    for (int n = 0; n < 4; n++) {
      int row = n * 16 + fr;
#pragma unroll
      for (int kd = 0; kd < 4; kd++) {
        int pb = (kd * 4 + g) ^ (fr & 7);
        bf16x8 kf = *(const bf16x8*)&Ks[buf][row * 128 + pb * 8];
        acc[n] = __builtin_amdgcn_mfma_f32_16x16x32_bf16(qf[kd], kf, acc[n], 0, 0, 0);
      }
    }

    // online softmax (per q-row r); lrun stays per-lane partial
    float corr[4];
#pragma unroll
    for (int r = 0; r < 4; r++) {
      float pm = fmaxf(fmaxf(acc[0][r], acc[1][r]), fmaxf(acc[2][r], acc[3][r])) * sc;
#pragma unroll
      for (int off = 1; off < 16; off <<= 1) pm = fmaxf(pm, __shfl_xor(pm, off));
      float mn = fmaxf(mrun[r], pm);
      corr[r] = __expf(mrun[r] - mn);
      mrun[r] = mn;
      float psum = 0.f;
      int qrow = g * 4 + r;
#pragma unroll
      for (int n = 0; n < 4; n++) {
        float p = __expf(acc[n][r] * sc - mn);
        psum += p;
        P[qrow * 72 + n * 16 + fr] = f2bf(p);
      }
      lrun[r] = lrun[r] * corr[r] + psum;
    }
#pragma unroll
    for (int nn = 0; nn < 8; nn++) {
      o[nn][0] *= corr[0]; o[nn][1] *= corr[1];
      o[nn][2] *= corr[2]; o[nn][3] *= corr[3];
    }

    // PV: o[nn][r] += P[q][kv] * VT[d=nn*16+fr][kv]
#pragma unroll
    for (int half = 0; half < 2; half++) {
      bf16x8 pa = *(const bf16x8*)&P[fr * 72 + half * 32 + fkb];
      const u16* vcol = Vt + c * 64 + half * 32 + fkb;
#pragma unroll
      for (int nn = 0; nn < 8; nn++) {
        bf16x8 vf = *(const bf16x8*)(vcol + (size_t)(nn * 16 + fr) * 1024);
        o[nn] = __builtin_amdgcn_mfma_f32_16x16x32_bf16(pa, vf, o[nn], 0, 0, 0);
      }
    }

    __syncthreads();
    buf ^= 1;
  }

  // final l reduction over fr lanes, then normalize + store
#pragma unroll
  for (int r = 0; r < 4; r++) {
    float lt = lrun[r];
#pragma unroll
    for (int off = 1; off < 16; off <<= 1) lt += __shfl_xor(lt, off);
    float inv = 1.0f / lt;
    int row = b * SQ + q0 + g * 4 + r;
    u16* Or = O + (size_t)row * 2048 + h * 128;
#pragma unroll
    for (int nn = 0; nn < 8; nn++) Or[nn * 16 + fr] = f2bf(o[nn][r] * inv);
  }
}

// ---------------- launch ----------------
extern "C" void kernel_launch(void* const* d_in, const int* in_sizes, int n_in,
                              void* d_out, int out_size, void* d_ws, size_t ws_size,
                              hipStream_t stream) {
  const float* image_embeds  = (const float*)d_in[0];  // [2,1024,2048]
  const float* hidden_states = (const float*)d_in[1];  // [2,2048,3072]
  const float* Wq   = (const float*)d_in[2];           // [3072,2048]
  const float* Wkv  = (const float*)d_in[3];           // [2048,4096]
  const float* Wout = (const float*)d_in[4];           // [2048,3072]
  const float* ln1_g = (const float*)d_in[5];
  const float* ln1_b = (const float*)d_in[6];
  const float* ln2_g = (const float*)d_in[7];
  const float* ln2_b = (const float*)d_in[8];
  float* out = (float*)d_out;

  char* ws = (char*)d_ws;
  size_t off = 0;
  auto alloc = [&](size_t bytes) {
    void* p = ws + off;
    off += (bytes + 255) & ~(size_t)255;
    return p;
  };
  u16* Xq   = (u16*)alloc((size_t)4096 * 3072 * 2);  // LN(hidden) bf16; reused as AO
  u16* Xkv  = (u16*)alloc((size_t)2048 * 2048 * 2);  // LN(image) bf16
  u16* WqT  = (u16*)alloc((size_t)2048 * 3072 * 2);  // Wq^T bf16; reused as VT
  u16* WkvT = (u16*)alloc((size_t)4096 * 2048 * 2);  // Wkv^T bf16
  u16* WoT  = (u16*)alloc((size_t)3072 * 2048 * 2);  // Wout^T bf16
  u16* Qb   = (u16*)alloc((size_t)4096 * 2048 * 2);  // q bf16
  u16* KVb  = (u16*)alloc((size_t)2048 * 4096 * 2);  // kv bf16
  u16* VTb  = WqT;   // alias: WqT dead after q-gemm
  u16* AO   = Xq;    // alias: Xq dead after q-gemm

  ln_cast<3><<<4096, 256, 0, stream>>>(hidden_states, ln2_g, ln2_b, Xq, 3072);
  ln_cast<2><<<2048, 256, 0, stream>>>(image_embeds, ln1_g, ln1_b, Xkv, 2048);
  transpose_cast<<<dim3(2048 / 32, 3072 / 32), 256, 0, stream>>>(Wq, WqT, 3072, 2048);
  transpose_cast<<<dim3(4096 / 32, 2048 / 32), 256, 0, stream>>>(Wkv, WkvT, 2048, 4096);
  transpose_cast<<<dim3(3072 / 32, 2048 / 32), 256, 0, stream>>>(Wout, WoT, 2048, 3072);

  gemm_bt<u16><<<(4096 / 128) * (2048 / 128), 256, 0, stream>>>(Xq, WqT, Qb, 4096, 2048, 3072);
  gemm_bt<u16><<<(2048 / 128) * (4096 / 128), 256, 0, stream>>>(Xkv, WkvT, KVb, 2048, 4096, 2048);

  build_vt<<<dim3(4, 32, 32), 256, 0, stream>>>(KVb, VTb);
  attn_kernel<<<32 * 32, 256, 0, stream>>>(Qb, KVb, VTb, AO);

  gemm_bt<float><<<(4096 / 128) * (3072 / 128), 256, 0, stream>>>(AO, WoT, out, 4096, 3072, 2048);
}

// Round 3
// 375.076 us; speedup vs baseline: 1.4851x; 1.2035x over previous
//
#include <hip/hip_runtime.h>
#include <hip/hip_bf16.h>

typedef unsigned short u16;
typedef __attribute__((ext_vector_type(8))) __bf16 bf16x8;
typedef __attribute__((ext_vector_type(4))) float f32x4;

#define DEV __device__ __forceinline__

DEV u16 f2bf(float f) {
  union { float f; unsigned int u; } v; v.f = f;
  unsigned int x = v.u;
  return (u16)((x + 0x7fffu + ((x >> 16) & 1u)) >> 16);  // RNE
}

DEV void gload_lds16(const u16* g, u16* l) {
  __builtin_amdgcn_global_load_lds(
      (__attribute__((address_space(1))) void*)(g),
      (__attribute__((address_space(3))) void*)(l), 16, 0, 0);
}

// ---------------- LayerNorm + cast to bf16 ----------------
template <int NV>
__global__ __launch_bounds__(256) void ln_cast(const float* __restrict__ x,
                                               const float* __restrict__ g,
                                               const float* __restrict__ b,
                                               u16* __restrict__ out, int C) {
  int row = blockIdx.x;
  int tid = threadIdx.x;
  const float4* xr = (const float4*)(x + (size_t)row * C);
  float4 v[NV];
  float s = 0.f, ss = 0.f;
#pragma unroll
  for (int i = 0; i < NV; i++) {
    v[i] = xr[tid + i * 256];
    s += v[i].x + v[i].y + v[i].z + v[i].w;
    ss += v[i].x * v[i].x + v[i].y * v[i].y + v[i].z * v[i].z + v[i].w * v[i].w;
  }
#pragma unroll
  for (int off = 32; off > 0; off >>= 1) {
    s += __shfl_down(s, off);
    ss += __shfl_down(ss, off);
  }
  __shared__ float red[8];
  int wv = tid >> 6;
  if ((tid & 63) == 0) { red[wv] = s; red[4 + wv] = ss; }
  __syncthreads();
  float S = red[0] + red[1] + red[2] + red[3];
  float SS = red[4] + red[5] + red[6] + red[7];
  float mu = S / C;
  float rstd = rsqrtf(SS / C - mu * mu + 1e-5f);
  const float4* gr = (const float4*)g;
  const float4* br = (const float4*)b;
  ushort4* orow = (ushort4*)(out + (size_t)row * C);
#pragma unroll
  for (int i = 0; i < NV; i++) {
    int gi = tid + i * 256;
    float4 gv = gr[gi], bv = br[gi];
    ushort4 o;
    o.x = f2bf((v[i].x - mu) * rstd * gv.x + bv.x);
    o.y = f2bf((v[i].y - mu) * rstd * gv.y + bv.y);
    o.z = f2bf((v[i].z - mu) * rstd * gv.z + bv.z);
    o.w = f2bf((v[i].w - mu) * rstd * gv.w + bv.w);
    orow[gi] = o;
  }
}

// ---------------- transpose + cast f32 -> bf16 ----------------
__global__ __launch_bounds__(256) void transpose_cast(const float* __restrict__ in,
                                                      u16* __restrict__ out,
                                                      int K, int N) {
  __shared__ float t[32][33];
  int tx = threadIdx.x & 31, ty = threadIdx.x >> 5;
  int n0 = blockIdx.x * 32, k0 = blockIdx.y * 32;
#pragma unroll
  for (int i = 0; i < 32; i += 8)
    t[ty + i][tx] = in[(size_t)(k0 + ty + i) * N + n0 + tx];
  __syncthreads();
#pragma unroll
  for (int i = 0; i < 32; i += 8)
    out[(size_t)(n0 + ty + i) * K + k0 + tx] = f2bf(t[tx][ty + i]);
}

// ---------------- build VT[bh][128][1024] from KV ----------------
__global__ __launch_bounds__(256) void build_vt(const u16* __restrict__ KV,
                                                u16* __restrict__ VT) {
  __shared__ u16 t[32][33];
  int bh = blockIdx.z, b = bh >> 4, h = bh & 15;
  int d0 = blockIdx.x * 32, s0 = blockIdx.y * 32;
  int tx = threadIdx.x & 31, ty = threadIdx.x >> 5;
  const u16* src = KV + (size_t)(b * 1024) * 4096 + 2048 + h * 128;
#pragma unroll
  for (int i = 0; i < 32; i += 8)
    t[ty + i][tx] = src[(size_t)(s0 + ty + i) * 4096 + d0 + tx];
  __syncthreads();
  u16* dst = VT + (size_t)bh * (128 * 1024);
#pragma unroll
  for (int i = 0; i < 32; i += 8)
    dst[(size_t)(d0 + ty + i) * 1024 + s0 + tx] = t[tx][ty + i];
}

// ---------------- GEMM: C[M,N] = oscale * A[M,K] * BT[N,K]^T ----------------
DEV void storeC(u16* C, size_t idx, float v) { C[idx] = f2bf(v); }
DEV void storeC(float* C, size_t idx, float v) { C[idx] = v; }

template <typename OutT>
__global__ __launch_bounds__(256) void gemm_bt(const u16* __restrict__ A,
                                               const u16* __restrict__ BT,
                                               OutT* __restrict__ C,
                                               int M, int N, int K, float oscale) {
  constexpr int BK = 32;
  __shared__ __attribute__((aligned(16))) u16 As[128 * BK];
  __shared__ __attribute__((aligned(16))) u16 Bs[128 * BK];
  int tilesN = N >> 7;
  int bm = (blockIdx.x / tilesN) << 7;
  int bn = (blockIdx.x % tilesN) << 7;
  int tid = threadIdx.x;
  int lane = tid & 63, wave = tid >> 6;
  int wm = (wave >> 1) << 6, wn = (wave & 1) << 6;
  int srow = wave * 16 + (lane >> 2);
  int scol = (lane & 3) * 8;
  int fr = lane & 15, fk = (lane >> 4) * 8;
  const u16* Ab = A + (size_t)bm * K;
  const u16* Bb = BT + (size_t)bn * K;
  f32x4 acc[4][4] = {};

  for (int kt = 0; kt < K; kt += BK) {
#pragma unroll
    for (int j = 0; j < 2; j++) {
      gload_lds16(Ab + (size_t)(j * 64 + srow) * K + kt + scol,
                  &As[(j * 64 + wave * 16) * BK]);
      gload_lds16(Bb + (size_t)(j * 64 + srow) * K + kt + scol,
                  &Bs[(j * 64 + wave * 16) * BK]);
    }
    __syncthreads();
    bf16x8 af[4], bfr[4];
#pragma unroll
    for (int m = 0; m < 4; m++)
      af[m] = *(const bf16x8*)&As[(wm + m * 16 + fr) * BK + fk];
#pragma unroll
    for (int n = 0; n < 4; n++)
      bfr[n] = *(const bf16x8*)&Bs[(wn + n * 16 + fr) * BK + fk];
#pragma unroll
    for (int m = 0; m < 4; m++)
#pragma unroll
      for (int n = 0; n < 4; n++)
        acc[m][n] = __builtin_amdgcn_mfma_f32_16x16x32_bf16(af[m], bfr[n], acc[m][n], 0, 0, 0);
    __syncthreads();
  }

#pragma unroll
  for (int m = 0; m < 4; m++) {
    int rbase = bm + wm + m * 16 + ((lane >> 4) << 2);
#pragma unroll
    for (int n = 0; n < 4; n++) {
      int col = bn + wn + n * 16 + fr;
#pragma unroll
      for (int r = 0; r < 4; r++)
        storeC(C, (size_t)(rbase + r) * N + col, acc[m][n][r] * oscale);
    }
  }
}

// ---------------- fused flash attention (v3) ----------------
// 4 waves x 32 q-rows (2 q-groups of 16) = 128 q-rows per block.
// K staged in LDS (dbuf, swizzled source); V prefetched to regs per chunk.
// Q is pre-scaled by 1/sqrt(128) in the q-GEMM epilogue.
// grid = B*H * (SQ/128) = 512 blocks.
__global__ __launch_bounds__(256) void attn_kernel(const u16* __restrict__ Q,
                                                   const u16* __restrict__ KV,
                                                   const u16* __restrict__ VT,
                                                   u16* __restrict__ O) {
  const int SQ = 2048, SKV = 1024;
  const int NCHUNK = SKV / 64;
  int qt = blockIdx.x & 15, bh = blockIdx.x >> 4;
  int b = bh >> 4, h = bh & 15;
  int wave = threadIdx.x >> 6, lane = threadIdx.x & 63;
  int q0 = qt * 128 + wave * 32;
  int fr = lane & 15, g = lane >> 4, fkb = g * 8;

  __shared__ __attribute__((aligned(16))) u16 Ks[2][64 * 128];
  __shared__ __attribute__((aligned(16))) u16 Pb[4][32 * 72];  // 72 = 64 + pad
  u16* P = &Pb[wave][0];

  // Q fragments: 2 q-groups x 4 k-slices
  bf16x8 qf[2][4];
#pragma unroll
  for (int gq = 0; gq < 2; gq++) {
    const u16* Qbase = Q + (size_t)(b * SQ + q0 + gq * 16 + fr) * 2048 + h * 128;
#pragma unroll
    for (int kd = 0; kd < 4; kd++)
      qf[gq][kd] = *(const bf16x8*)(Qbase + kd * 32 + fkb);
  }

  const u16* Kb = KV + (size_t)(b * SKV) * 4096 + h * 128;
  const u16* Vt = VT + (size_t)bh * (128 * 1024);

  auto stage = [&](int c, int buf) {
#pragma unroll
    for (int j = 0; j < 4; j++) {
      int r = wave * 16 + j * 4 + g;
      int gb = (lane & 15) ^ (r & 7);
      gload_lds16(Kb + (size_t)(c * 64 + r) * 4096 + gb * 8,
                  &Ks[buf][(wave * 16 + j * 4) * 128]);
    }
  };

  f32x4 o[2][8] = {};
  float mrun[2][4] = {{-1e30f, -1e30f, -1e30f, -1e30f},
                      {-1e30f, -1e30f, -1e30f, -1e30f}};
  float lrun[2][4] = {};

  stage(0, 0);
  __syncthreads();
  int buf = 0;

  for (int c = 0; c < NCHUNK; c++) {
    if (c + 1 < NCHUNK) stage(c + 1, buf ^ 1);

    // QK^T: acc[gq][n][r] = S[q = gq*16 + g*4 + r][kv = n*16 + fr]
    f32x4 acc[2][4] = {};
#pragma unroll
    for (int n = 0; n < 4; n++) {
      int row = n * 16 + fr;
#pragma unroll
      for (int kd = 0; kd < 4; kd++) {
        int pb = (kd * 4 + g) ^ (fr & 7);
        bf16x8 kf = *(const bf16x8*)&Ks[buf][row * 128 + pb * 8];
        acc[0][n] = __builtin_amdgcn_mfma_f32_16x16x32_bf16(qf[0][kd], kf, acc[0][n], 0, 0, 0);
        acc[1][n] = __builtin_amdgcn_mfma_f32_16x16x32_bf16(qf[1][kd], kf, acc[1][n], 0, 0, 0);
      }
    }

    // prefetch V for this chunk (latency hides under softmax)
    bf16x8 vf0[8], vf1[8];
#pragma unroll
    for (int nn = 0; nn < 8; nn++) {
      const u16* vrow = Vt + (size_t)(nn * 16 + fr) * 1024 + c * 64 + fkb;
      vf0[nn] = *(const bf16x8*)(vrow);
      vf1[nn] = *(const bf16x8*)(vrow + 32);
    }

    // online softmax (per q-row), lrun kept per-lane partial
    float corr[2][4];
#pragma unroll
    for (int gq = 0; gq < 2; gq++) {
#pragma unroll
      for (int r = 0; r < 4; r++) {
        float pm = fmaxf(fmaxf(acc[gq][0][r], acc[gq][1][r]),
                         fmaxf(acc[gq][2][r], acc[gq][3][r]));
#pragma unroll
        for (int off = 1; off < 16; off <<= 1) pm = fmaxf(pm, __shfl_xor(pm, off));
        float mn = fmaxf(mrun[gq][r], pm);
        corr[gq][r] = __expf(mrun[gq][r] - mn);
        mrun[gq][r] = mn;
        float psum = 0.f;
        int qrow = gq * 16 + g * 4 + r;
#pragma unroll
        for (int n = 0; n < 4; n++) {
          float p = __expf(acc[gq][n][r] - mn);
          psum += p;
          P[qrow * 72 + n * 16 + fr] = f2bf(p);
        }
        lrun[gq][r] = lrun[gq][r] * corr[gq][r] + psum;
      }
    }
#pragma unroll
    for (int gq = 0; gq < 2; gq++)
#pragma unroll
      for (int nn = 0; nn < 8; nn++) {
        o[gq][nn][0] *= corr[gq][0]; o[gq][nn][1] *= corr[gq][1];
        o[gq][nn][2] *= corr[gq][2]; o[gq][nn][3] *= corr[gq][3];
      }

    // PV (P is per-wave in LDS; drain ds_writes before reading)
    asm volatile("s_waitcnt lgkmcnt(0)" ::: "memory");
    {
      bf16x8 pa0 = *(const bf16x8*)&P[fr * 72 + fkb];
      bf16x8 pa1 = *(const bf16x8*)&P[(16 + fr) * 72 + fkb];
#pragma unroll
      for (int nn = 0; nn < 8; nn++) {
        o[0][nn] = __builtin_amdgcn_mfma_f32_16x16x32_bf16(pa0, vf0[nn], o[0][nn], 0, 0, 0);
        o[1][nn] = __builtin_amdgcn_mfma_f32_16x16x32_bf16(pa1, vf0[nn], o[1][nn], 0, 0, 0);
      }
      pa0 = *(const bf16x8*)&P[fr * 72 + 32 + fkb];
      pa1 = *(const bf16x8*)&P[(16 + fr) * 72 + 32 + fkb];
#pragma unroll
      for (int nn = 0; nn < 8; nn++) {
        o[0][nn] = __builtin_amdgcn_mfma_f32_16x16x32_bf16(pa0, vf1[nn], o[0][nn], 0, 0, 0);
        o[1][nn] = __builtin_amdgcn_mfma_f32_16x16x32_bf16(pa1, vf1[nn], o[1][nn], 0, 0, 0);
      }
    }

    __syncthreads();
    buf ^= 1;
  }

  // final l reduction over fr lanes, then normalize + store
#pragma unroll
  for (int gq = 0; gq < 2; gq++)
#pragma unroll
    for (int r = 0; r < 4; r++) {
      float lt = lrun[gq][r];
#pragma unroll
      for (int off = 1; off < 16; off <<= 1) lt += __shfl_xor(lt, off);
      float inv = 1.0f / lt;
      int row = b * SQ + q0 + gq * 16 + g * 4 + r;
      u16* Or = O + (size_t)row * 2048 + h * 128;
#pragma unroll
      for (int nn = 0; nn < 8; nn++) Or[nn * 16 + fr] = f2bf(o[gq][nn][r] * inv);
    }
}

// ---------------- launch ----------------
extern "C" void kernel_launch(void* const* d_in, const int* in_sizes, int n_in,
                              void* d_out, int out_size, void* d_ws, size_t ws_size,
                              hipStream_t stream) {
  const float* image_embeds  = (const float*)d_in[0];  // [2,1024,2048]
  const float* hidden_states = (const float*)d_in[1];  // [2,2048,3072]
  const float* Wq   = (const float*)d_in[2];           // [3072,2048]
  const float* Wkv  = (const float*)d_in[3];           // [2048,4096]
  const float* Wout = (const float*)d_in[4];           // [2048,3072]
  const float* ln1_g = (const float*)d_in[5];
  const float* ln1_b = (const float*)d_in[6];
  const float* ln2_g = (const float*)d_in[7];
  const float* ln2_b = (const float*)d_in[8];
  float* out = (float*)d_out;

  char* ws = (char*)d_ws;
  size_t off = 0;
  auto alloc = [&](size_t bytes) {
    void* p = ws + off;
    off += (bytes + 255) & ~(size_t)255;
    return p;
  };
  u16* Xq   = (u16*)alloc((size_t)4096 * 3072 * 2);  // LN(hidden) bf16; reused as AO
  u16* Xkv  = (u16*)alloc((size_t)2048 * 2048 * 2);  // LN(image) bf16
  u16* WqT  = (u16*)alloc((size_t)2048 * 3072 * 2);  // Wq^T bf16; reused as VT
  u16* WkvT = (u16*)alloc((size_t)4096 * 2048 * 2);  // Wkv^T bf16
  u16* WoT  = (u16*)alloc((size_t)3072 * 2048 * 2);  // Wout^T bf16
  u16* Qb   = (u16*)alloc((size_t)4096 * 2048 * 2);  // q bf16 (pre-scaled)
  u16* KVb  = (u16*)alloc((size_t)2048 * 4096 * 2);  // kv bf16
  u16* VTb  = WqT;   // alias: WqT dead after q-gemm
  u16* AO   = Xq;    // alias: Xq dead after q-gemm

  const float qscale = 0.08838834764831845f;  // 1/sqrt(128)

  ln_cast<3><<<4096, 256, 0, stream>>>(hidden_states, ln2_g, ln2_b, Xq, 3072);
  ln_cast<2><<<2048, 256, 0, stream>>>(image_embeds, ln1_g, ln1_b, Xkv, 2048);
  transpose_cast<<<dim3(2048 / 32, 3072 / 32), 256, 0, stream>>>(Wq, WqT, 3072, 2048);
  transpose_cast<<<dim3(4096 / 32, 2048 / 32), 256, 0, stream>>>(Wkv, WkvT, 2048, 4096);
  transpose_cast<<<dim3(3072 / 32, 2048 / 32), 256, 0, stream>>>(Wout, WoT, 2048, 3072);

  gemm_bt<u16><<<(4096 / 128) * (2048 / 128), 256, 0, stream>>>(Xq, WqT, Qb, 4096, 2048, 3072, qscale);
  gemm_bt<u16><<<(2048 / 128) * (4096 / 128), 256, 0, stream>>>(Xkv, WkvT, KVb, 2048, 4096, 2048, 1.0f);

  build_vt<<<dim3(4, 32, 32), 256, 0, stream>>>(KVb, VTb);
  attn_kernel<<<512, 256, 0, stream>>>(Qb, KVb, VTb, AO);

  gemm_bt<float><<<(4096 / 128) * (3072 / 128), 256, 0, stream>>>(AO, WoT, out, 4096, 3072, 2048, 1.0f);
}